// Round 8
// baseline (240.668 us; speedup 1.0000x reference)
//
#include <hip/hip_runtime.h>

// B = 16777216 rows, 2 cols. 2048 blocks x 8192 elems.
// Phase 1 streams via global_load_lds (async DMA) with explicit vmcnt pipelining.
#define E_BLOCK 8192
#define E_WAVE  2048
#define SUB     512            // elems per subtile per wave
#define NSUB    4              // E_WAVE / SUB
#define QITERS  8              // slow-path iterations (4 elems each)

#define M1f     0.2771814156f  // 0.5*(85/900)^0.25  (class-1 LDAM margin)
#define C_A1    60.0f
#define C_C1    (30.0f*M1f - 15.0f)

#define EXP2F(v) __builtin_amdgcn_exp2f(v)   // v_exp_f32: 2^x
#define LOG2F(v) __builtin_amdgcn_logf(v)    // v_log_f32: log2(x)

// s_waitcnt imm (gfx9 encoding): vmcnt[3:0]|expcnt<<4|lgkmcnt<<8|vmcnt[5:4]<<14
#define VMCNT_IMM(N) (((N)&15) | (((N)>>4)<<14) | (7<<4) | (15<<8))

struct BlockRec {
  int s0, p0, s1, p1;
  float wnll, fl;
  int cnt1, pad;
};

__device__ __forceinline__ void comb0(int &s, int &f, int &l, int sb, int fb, int lb) {
  s += sb + l * fb;
  f = f ? f : fb;
  l = fb ? lb : l;
}

__device__ __forceinline__ void bfly_step(int m, int lane, int &s, int &f, int &l) {
  const int os = __shfl_xor(s, m), of = __shfl_xor(f, m), ol = __shfl_xor(l, m);
  const bool up = (lane & m) != 0;
  int as = up ? os : s, af = up ? of : f, al = up ? ol : l;
  const int bs = up ? s : os, bf = up ? f : of, bl = up ? l : ol;
  comb0(as, af, al, bs, bf, bl);
  s = as; f = af; l = al;
}

__device__ __forceinline__ void elem_math(float x0, float x1, int t, int k,
                                          float &wnll, float &flraw, int &cnt1,
                                          unsigned int &word) {
  const float tf  = (float)t;
  const float wgt = fmaf(tf, 0.7f, 0.15f);
  const float d   = x0 - x1;
  const float za  = fmaf(tf, C_A1, -30.0f);
  const float zc  = fmaf(tf, C_C1, 15.0f);
  const float z   = fmaf(za, d, zc);
  const float ex  = EXP2F(fabsf(z) * -1.44269504f);
  const float lp  = LOG2F(1.0f + ex);
  const float sp  = fmaf(0.69314718f, lp, fmaxf(z, 0.0f));
  wnll = fmaf(wgt, sp, wnll);
  const float om  = 1.0f - x1;
  const float q   = t ? x1 : om;
  const float r   = t ? om : x1;
  const float lg2 = LOG2F(q + 1e-9f);
  const float wr2 = (wgt * r) * r;
  flraw = fmaf(wr2, lg2, flraw);
  cnt1 += t;
  const unsigned int code = 4u | (unsigned int)(d > 0.0f) | ((unsigned int)t << 1);
  word |= code << (8 * k);
}

__device__ __forceinline__ void load_lds16f(const float* g, unsigned int* l) {
  __builtin_amdgcn_global_load_lds(
      (const __attribute__((address_space(1))) void*)g,
      (__attribute__((address_space(3))) void*)l, 16, 0, 0);
}
__device__ __forceinline__ void load_lds16i(const int* g, unsigned int* l) {
  __builtin_amdgcn_global_load_lds(
      (const __attribute__((address_space(1))) void*)g,
      (__attribute__((address_space(3))) void*)l, 16, 0, 0);
}

__global__ __launch_bounds__(256, 2) void loss_pass1(
    const float* __restrict__ x, const int* __restrict__ tgt,
    BlockRec* __restrict__ recs, int B) {
  // LDS (words): [0,12288) streaming: per wave w 3072 words (12 KB), two buffers
  //   of 1536 words each (x:1024 + tgt:512). Aux: [12288,14592) chunk words
  //   (stride-9 padded), [14592,14848) stw, [14848,15104) wnll, [15104,15360) fls,
  //   [15360,15616) cnt.  Total 62464 B -> 2 blocks/CU.
  __shared__ unsigned int lds[15616];
  unsigned int* chunkw = lds + 12288;
  unsigned int* stw = lds + 14592;
  float* wnw = (float*)(lds + 14848);
  float* flw = (float*)(lds + 15104);
  int*   cnw = (int*)(lds + 15360);

  const int tid = threadIdx.x;
  const int w = tid >> 6, lane = tid & 63;
  const int waveBase = blockIdx.x * E_BLOCK + w * E_WAVE;

  float wnll = 0.f, flraw = 0.f; int cnt1 = 0;

  if (waveBase + E_WAVE <= B) {
    // ---- async-DMA double-buffered stream; per-wave private LDS, no barriers ----
    unsigned int* const wbase = lds + w * 3072;

    // issue one subtile's 6 DMA instructions (6 KB)
    auto issue = [&](int s, int bsel) {
      const int sb = waveBase + s * SUB;
      unsigned int* lbx = wbase + bsel * 1536;
      unsigned int* lbt = lbx + 1024;
      #pragma unroll
      for (int i = 0; i < 4; ++i)     // x: 4 x 1KB (128 elems each)
        load_lds16f(x + 2 * (size_t)sb + i * 256 + lane * 4, lbx + i * 256);
      #pragma unroll
      for (int i = 0; i < 2; ++i)     // tgt: 2 x 1KB (256 elems each)
        load_lds16i(tgt + sb + i * 256 + lane * 4, lbt + i * 256);
    };

    issue(0, 0);
    issue(1, 1);                      // 12 DMA in flight

    #pragma unroll
    for (int s = 0; s < NSUB; ++s) {
      if (s < NSUB - 1) __builtin_amdgcn_s_waitcnt(VMCNT_IMM(6));  // subtile s landed
      else              __builtin_amdgcn_s_waitcnt(VMCNT_IMM(0));
      const char* lbx = (const char*)(wbase + (s & 1) * 1536);
      const char* lbt = lbx + 4096;
      #pragma unroll
      for (int h = 0; h < 2; ++h) {   // each lane: quads lane and lane+64
        const int qq = lane + h * 64;
        const float4 xa = *(const float4*)(lbx + qq * 32);
        const float4 xb = *(const float4*)(lbx + qq * 32 + 16);
        const int4  t4 = *(const int4*)(lbt + qq * 16);
        unsigned int word = 0;
        elem_math(xa.x, xa.y, t4.x, 0, wnll, flraw, cnt1, word);
        elem_math(xa.z, xa.w, t4.y, 1, wnll, flraw, cnt1, word);
        elem_math(xb.x, xb.y, t4.z, 2, wnll, flraw, cnt1, word);
        elem_math(xb.z, xb.w, t4.w, 3, wnll, flraw, cnt1, word);
        const int qi = w * 512 + s * 128 + qq;
        chunkw[(qi >> 3) * 9 + (qi & 7)] = word;
      }
      if (s + 2 < NSUB) issue(s + 2, s & 1);   // refill the buffer just consumed
    }
  } else {
    // slow path: per-element guard (only a partial tail block)
    for (int j = 0; j < QITERS; ++j) {
      unsigned int word = 0;
      for (int k = 0; k < 4; ++k) {
        const int e = waveBase + ((j << 6) + lane) * 4 + k;
        if (e < B) {
          elem_math(x[2 * (size_t)e], x[2 * (size_t)e + 1], tgt[e], k,
                    wnll, flraw, cnt1, word);
        }
      }
      const int qi = w * 512 + (j << 6) + lane;
      chunkw[(qi >> 3) * 9 + (qi & 7)] = word;
    }
  }
  __syncthreads();

  // Phase 2: each thread serially chains its contiguous 32-element chunk.
  int s0 = 0, f0 = 0, l0 = 0, s1 = 0, f1 = 0, l1 = 0;
  #pragma unroll
  for (int r = 0; r < 8; ++r) {
    const unsigned int wv = chunkw[tid * 9 + r];
    #pragma unroll
    for (int k = 0; k < 4; ++k) {
      const unsigned int b = (wv >> (8 * k)) & 7u;
      if (b & 4u) {
        const int sv = (int)((b & 1u) << 1) - 1;
        const int t  = (int)((b >> 1) & 1u);
        const int lv = t ? l1 : l0;
        const int add = lv * sv;
        if (t) { s1 += add; l1 = sv; f1 = f1 ? f1 : sv; }
        else   { s0 += add; l0 = sv; f0 = f0 ? f0 : sv; }
      }
    }
  }
  stw[tid] = (unsigned)(s0 + 128) | ((unsigned)(f0 + 1) << 8) | ((unsigned)(l0 + 1) << 10)
           | ((unsigned)(s1 + 128) << 16) | ((unsigned)(f1 + 1) << 24) | ((unsigned)(l1 + 1) << 26);
  wnw[tid] = wnll; flw[tid] = flraw * -0.69314718f; cnw[tid] = cnt1;
  __syncthreads();

  if (w == 0) {
    int S0 = 0, F0 = 0, L0 = 0, S1 = 0, F1 = 0, L1 = 0;
    float W = 0.f, F = 0.f; int C = 0;
    #pragma unroll
    for (int q = 0; q < 4; ++q) {
      const int i = lane * 4 + q;
      const unsigned int pk = stw[i];
      comb0(S0, F0, L0, (int)(pk & 255u) - 128, (int)((pk >> 8) & 3u) - 1, (int)((pk >> 10) & 3u) - 1);
      comb0(S1, F1, L1, (int)((pk >> 16) & 255u) - 128, (int)((pk >> 24) & 3u) - 1, (int)((pk >> 26) & 3u) - 1);
      W += wnw[i]; F += flw[i]; C += cnw[i];
    }
    #pragma unroll
    for (int k = 0; k < 6; ++k) {
      const int m = 1 << k;
      bfly_step(m, lane, S0, F0, L0);
      bfly_step(m, lane, S1, F1, L1);
      W += __shfl_xor(W, m); F += __shfl_xor(F, m); C += __shfl_xor(C, m);
    }
    if (lane == 0) {
      BlockRec r;
      r.s0 = S0; r.p0 = (F0 + 1) | ((L0 + 1) << 4);
      r.s1 = S1; r.p1 = (F1 + 1) | ((L1 + 1) << 4);
      r.wnll = W; r.fl = F; r.cnt1 = C; r.pad = 0;
      recs[blockIdx.x] = r;
    }
  }
}

__global__ __launch_bounds__(256) void loss_pass2(
    const BlockRec* __restrict__ recs, int NB, int B, float* __restrict__ out) {
  __shared__ int sS0[256], sF0[256], sL0[256], sS1[256], sF1[256], sL1[256], sC[256];
  __shared__ double sW[256], sFl[256];
  const int tid = threadIdx.x, w = tid >> 6, lane = tid & 63;
  const int R = (NB + 255) >> 8;

  int s0 = 0, f0 = 0, l0 = 0, s1 = 0, f1 = 0, l1 = 0;
  double W = 0.0, Fd = 0.0; int C = 0;
  for (int r = 0; r < R; ++r) {
    const int b = tid * R + r;
    if (b < NB) {
      const BlockRec rec = recs[b];
      comb0(s0, f0, l0, rec.s0, (rec.p0 & 3) - 1, ((rec.p0 >> 4) & 3) - 1);
      comb0(s1, f1, l1, rec.s1, (rec.p1 & 3) - 1, ((rec.p1 >> 4) & 3) - 1);
      W += (double)rec.wnll; Fd += (double)rec.fl; C += rec.cnt1;
    }
  }
  sS0[tid] = s0; sF0[tid] = f0; sL0[tid] = l0;
  sS1[tid] = s1; sF1[tid] = f1; sL1[tid] = l1;
  sC[tid] = C; sW[tid] = W; sFl[tid] = Fd;
  __syncthreads();

  if (w == 0) {
    int S0 = 0, F0 = 0, L0 = 0, S1 = 0, F1 = 0, L1 = 0; int Ct = 0;
    double Wt = 0.0, Ft = 0.0;
    #pragma unroll
    for (int q = 0; q < 4; ++q) {
      const int i = lane * 4 + q;
      comb0(S0, F0, L0, sS0[i], sF0[i], sL0[i]);
      comb0(S1, F1, L1, sS1[i], sF1[i], sL1[i]);
      Wt += sW[i]; Ft += sFl[i]; Ct += sC[i];
    }
    #pragma unroll
    for (int k = 0; k < 6; ++k) {
      const int m = 1 << k;
      bfly_step(m, lane, S0, F0, L0);
      bfly_step(m, lane, S1, F1, L1);
      Wt += __shfl_xor(Wt, m); Ft += __shfl_xor(Ft, m); Ct += __shfl_xor(Ct, m);
    }
    if (lane == 0) {
      const double n1 = (double)Ct, n0 = (double)B - n1;
      const double sw = 0.15 * n0 + 0.85 * n1;
      const double ldam  = Wt / sw;
      const double focal = Ft / (double)B;
      const double q0 = (n0 > 0.0) ? (double)S0 / n0 : 0.0;
      const double q1 = (n1 > 0.0) ? (double)S1 / n1 : 0.0;
      const double dq = q0 - q1;
      out[0] = (float)(ldam + focal + dq * dq);
    }
  }
}

extern "C" void kernel_launch(void* const* d_in, const int* in_sizes, int n_in,
                              void* d_out, int out_size, void* d_ws, size_t ws_size,
                              hipStream_t stream) {
  const float* x  = (const float*)d_in[0];
  const int* tgt  = (const int*)d_in[1];
  float* out      = (float*)d_out;
  const int B  = in_sizes[1];                       // rows (16777216)
  const int NB = (B + E_BLOCK - 1) / E_BLOCK;       // 2048
  BlockRec* recs = (BlockRec*)d_ws;                 // 64 KB scratch
  loss_pass1<<<NB, 256, 0, stream>>>(x, tgt, recs, B);
  loss_pass2<<<1, 256, 0, stream>>>(recs, NB, B, out);
}